// Round 5
// baseline (64.780 us; speedup 1.0000x reference)
//
#include <hip/hip_runtime.h>
#include <hip/hip_fp16.h>

typedef _Float16 f16x8 __attribute__((ext_vector_type(8)));
typedef _Float16 f16x4 __attribute__((ext_vector_type(4)));
typedef float f32x4 __attribute__((ext_vector_type(4)));

// ---------------------------------------------------------------------------
// prep_weights: 128 blocks x 256 threads
//   WcT  f16 [128][256]: row o<64 = W_s col o; row 64+o = mean_m W_lin col o
//   Wt16 f16 [64][256] : W_t transposed
//   bmean f32 [64]     : mean_m b_lin
// ---------------------------------------------------------------------------
__global__ void prep_weights(const float* __restrict__ W_lin, const float* __restrict__ b_lin,
                             const float* __restrict__ W_s, const float* __restrict__ W_t,
                             _Float16* __restrict__ WcT, _Float16* __restrict__ Wt16,
                             float* __restrict__ bmean) {
    int tid = blockIdx.x * 256 + threadIdx.x;    // 32768 threads
    if (tid < 16384) {
        int c = tid >> 6, o = tid & 63;
        WcT[o * 256 + c]  = (_Float16)W_s[c * 64 + o];
        Wt16[o * 256 + c] = (_Float16)W_t[c * 64 + o];
    } else {
        int t = tid - 16384;
        int c = t >> 6, o = t & 63;
        float s = 0.f;
        #pragma unroll 8
        for (int m = 0; m < 64; ++m) s += W_lin[m * 16384 + c * 64 + o];
        WcT[(64 + o) * 256 + c] = (_Float16)(s * (1.f / 64.f));
    }
    if (tid < 64) {
        float s = 0.f;
        #pragma unroll 8
        for (int m = 0; m < 64; ++m) s += b_lin[m * 64 + tid];
        bmean[tid] = s * (1.f / 64.f);
    }
}

// ---------------------------------------------------------------------------
// gemm_prep: 2048 blocks x 256 threads (4 waves), NO LDS, NO BARRIER.
// Each block owns 16 A-rows; the 4 waves split output columns.
//  blocks 0..1023 (src): wave w -> nt {2w, 2w+1} of 8 col-tiles.
//     nt<4:  Ppe[row][nt*16+l15]      = exp(source@W_s)        f16
//     nt>=4: Ppe[row][nt*16+l15]      = source@W_mean + bmean  f16  (cols 64..127)
//  blocks 1024..2047 (tgt): wave w -> nt w of 4 col-tiles.
//     Et[row][w*16+l15] = exp(target@W_t + b_s + b_t)          f32
// B fragments read directly from L2 (WcT/Wt16 are tiny and hot).
// ---------------------------------------------------------------------------
__device__ __forceinline__ f16x8 cvt8(const float* p) {
    f32x4 x = *(const f32x4*)p;
    f32x4 y = *(const f32x4*)(p + 4);
    f16x8 h;
    h[0] = (_Float16)x[0]; h[1] = (_Float16)x[1]; h[2] = (_Float16)x[2]; h[3] = (_Float16)x[3];
    h[4] = (_Float16)y[0]; h[5] = (_Float16)y[1]; h[6] = (_Float16)y[2]; h[7] = (_Float16)y[3];
    return h;
}

__global__ __launch_bounds__(256, 4)
void gemm_prep(const float* __restrict__ source, const float* __restrict__ target,
               const _Float16* __restrict__ WcT, const _Float16* __restrict__ Wt16,
               const float* __restrict__ bmean, const float* __restrict__ b_s,
               const float* __restrict__ b_t,
               _Float16* __restrict__ Ppe, float* __restrict__ Et) {
    const int tid = threadIdx.x;
    const int w = tid >> 6, l = tid & 63;
    const int l15 = l & 15, lq = l >> 4;
    const int b = blockIdx.x;

    if (b < 1024) {
        // ---------------- SRC path: 16 rows x 128 cols, wave w -> nt 2w,2w+1
        const int rb = b * 16;
        const float* arow = source + (size_t)(rb + l15) * 256;
        f16x8 af[8];
        #pragma unroll
        for (int s = 0; s < 8; ++s) af[s] = cvt8(arow + s * 32 + lq * 8);

        const int nt0 = w * 2;
        const _Float16* b0p = WcT + (nt0 * 16 + l15) * 256 + lq * 8;
        const _Float16* b1p = b0p + 16 * 256;

        f32x4 acc[2] = {};
        #pragma unroll
        for (int s = 0; s < 8; ++s) {
            f16x8 b0 = *(const f16x8*)(b0p + s * 32);
            f16x8 b1 = *(const f16x8*)(b1p + s * 32);
            acc[0] = __builtin_amdgcn_mfma_f32_16x16x32_f16(af[s], b0, acc[0], 0, 0, 0);
            acc[1] = __builtin_amdgcn_mfma_f32_16x16x32_f16(af[s], b1, acc[1], 0, 0, 0);
        }

        const bool isPe = (nt0 < 4);                 // wave-uniform
        float addv[2];
        #pragma unroll
        for (int t = 0; t < 2; ++t)
            addv[t] = isPe ? 0.f : bmean[(nt0 + t - 4) * 16 + l15];

        #pragma unroll
        for (int j = 0; j < 4; ++j) {
            int row = rb + lq * 4 + j;
            #pragma unroll
            for (int t = 0; t < 2; ++t) {
                float v = acc[t][j];
                _Float16 r = isPe ? (_Float16)__expf(v) : (_Float16)(v + addv[t]);
                Ppe[row * 128 + (nt0 + t) * 16 + l15] = r;
            }
        }
    } else {
        // ---------------- TGT path: 16 rows x 64 cols, wave w -> nt w
        const int rb = (b - 1024) * 16;
        const float* arow = target + (size_t)(rb + l15) * 256;
        f16x8 af[8];
        #pragma unroll
        for (int s = 0; s < 8; ++s) af[s] = cvt8(arow + s * 32 + lq * 8);

        const _Float16* bp = Wt16 + (w * 16 + l15) * 256 + lq * 8;
        f32x4 acc = {};
        #pragma unroll
        for (int s = 0; s < 8; ++s) {
            f16x8 bf = *(const f16x8*)(bp + s * 32);
            acc = __builtin_amdgcn_mfma_f32_16x16x32_f16(af[s], bf, acc, 0, 0, 0);
        }

        const int col = w * 16 + l15;
        const float bsv = b_s[col] + b_t[col];
        #pragma unroll
        for (int j = 0; j < 4; ++j) {
            int row = rb + lq * 4 + j;
            Et[row * 64 + col] = __expf(acc[j] + bsv);
        }
    }
}

// ---------------------------------------------------------------------------
// epilogue: 4096 blocks x 256 threads; one target node n per wave (32 rows).
// Lane (lq,l15): group g handles 4 rows (lq) x 4 cols (l15*4..+3).
// out[r][o] = Pe[nb][o]*Et[n][o] / sum_o(Pe*Et) * Pp[nb][o]
// Ppe row = [Pe(64) | Pp(64)] f16. Output stored nontemporal (keep L2 for
// the gather tables).
// ---------------------------------------------------------------------------
__global__ __launch_bounds__(256)
void epilogue(const int* __restrict__ neighbors, const _Float16* __restrict__ Ppe,
              const float* __restrict__ Et, float* __restrict__ out) {
    const int tid = threadIdx.x;
    const int w = tid >> 6, l = tid & 63;
    const int lq = l >> 4, l15 = l & 15;
    const int n = blockIdx.x * 4 + w;
    const int co = l15 * 4;

    f32x4 et = *(const f32x4*)(Et + n * 64 + co);

    int nb[8];
    #pragma unroll
    for (int g = 0; g < 8; ++g) nb[g] = neighbors[n * 32 + g * 4 + lq];

    f16x4 pe[8], pp[8];
    #pragma unroll
    for (int g = 0; g < 2; ++g) {
        pe[g] = *(const f16x4*)(Ppe + nb[g] * 128 + co);
        pp[g] = *(const f16x4*)(Ppe + nb[g] * 128 + 64 + co);
    }

    #pragma unroll
    for (int g = 0; g < 8; ++g) {
        if (g + 2 < 8) {
            pe[g + 2] = *(const f16x4*)(Ppe + nb[g + 2] * 128 + co);
            pp[g + 2] = *(const f16x4*)(Ppe + nb[g + 2] * 128 + 64 + co);
        }
        float w0 = (float)pe[g][0] * et[0];
        float w1 = (float)pe[g][1] * et[1];
        float w2 = (float)pe[g][2] * et[2];
        float w3 = (float)pe[g][3] * et[3];
        float s = (w0 + w1) + (w2 + w3);
        s += __shfl_xor(s, 1);
        s += __shfl_xor(s, 2);
        s += __shfl_xor(s, 4);
        s += __shfl_xor(s, 8);
        float inv = 1.0f / s;
        f32x4 o;
        o[0] = w0 * inv * (float)pp[g][0];
        o[1] = w1 * inv * (float)pp[g][1];
        o[2] = w2 * inv * (float)pp[g][2];
        o[3] = w3 * inv * (float)pp[g][3];
        __builtin_nontemporal_store(o, (f32x4*)(out + (size_t)(n * 32 + g * 4 + lq) * 64 + co));
    }
}

// ---------------------------------------------------------------------------
extern "C" void kernel_launch(void* const* d_in, const int* in_sizes, int n_in,
                              void* d_out, int out_size, void* d_ws, size_t ws_size,
                              hipStream_t stream) {
    const float* source    = (const float*)d_in[0];
    const float* target    = (const float*)d_in[1];
    const int*   neighbors = (const int*)d_in[2];
    const float* W_lin     = (const float*)d_in[3];
    const float* b_lin     = (const float*)d_in[4];
    const float* W_s       = (const float*)d_in[5];
    const float* b_s       = (const float*)d_in[6];
    const float* W_t       = (const float*)d_in[7];
    const float* b_t       = (const float*)d_in[8];

    char* ws = (char*)d_ws;
    _Float16* Ppe   = (_Float16*)ws;                          // 4 MiB
    float*    Et    = (float*)(ws + (4u << 20));              // 4 MiB
    _Float16* WcT   = (_Float16*)(ws + (8u << 20));           // 64 KiB
    _Float16* Wt16  = (_Float16*)(ws + (8u << 20) + 65536);   // 32 KiB
    float*    bmean = (float*)(ws + (8u << 20) + 98304);      // 256 B
    float*    out   = (float*)d_out;

    prep_weights<<<128, 256, 0, stream>>>(W_lin, b_lin, W_s, W_t, WcT, Wt16, bmean);
    gemm_prep<<<2048, 256, 0, stream>>>(source, target, WcT, Wt16, bmean, b_s, b_t,
                                        Ppe, Et);
    epilogue<<<4096, 256, 0, stream>>>(neighbors, Ppe, Et, out);
}

// Round 6
// 54.126 us; speedup vs baseline: 1.1968x; 1.1968x over previous
//
#include <hip/hip_runtime.h>
#include <hip/hip_fp16.h>

typedef _Float16 f16x8 __attribute__((ext_vector_type(8)));
typedef _Float16 f16x4 __attribute__((ext_vector_type(4)));
typedef float f32x4 __attribute__((ext_vector_type(4)));

// ---------------------------------------------------------------------------
// prep_weights: 128 blocks x 256 threads
//   WcT  f16 [128][256]: row o<64 = W_s col o; row 64+o = mean_m W_lin col o
//   Wt16 f16 [64][256] : W_t transposed
//   bmean f32 [64]     : mean_m b_lin
// ---------------------------------------------------------------------------
__global__ void prep_weights(const float* __restrict__ W_lin, const float* __restrict__ b_lin,
                             const float* __restrict__ W_s, const float* __restrict__ W_t,
                             _Float16* __restrict__ WcT, _Float16* __restrict__ Wt16,
                             float* __restrict__ bmean) {
    int tid = blockIdx.x * 256 + threadIdx.x;    // 32768 threads
    if (tid < 16384) {
        int c = tid >> 6, o = tid & 63;
        WcT[o * 256 + c]  = (_Float16)W_s[c * 64 + o];
        Wt16[o * 256 + c] = (_Float16)W_t[c * 64 + o];
    } else {
        int t = tid - 16384;
        int c = t >> 6, o = t & 63;
        float s = 0.f;
        #pragma unroll 8
        for (int m = 0; m < 64; ++m) s += W_lin[m * 16384 + c * 64 + o];
        WcT[(64 + o) * 256 + c] = (_Float16)(s * (1.f / 64.f));
    }
    if (tid < 64) {
        float s = 0.f;
        #pragma unroll 8
        for (int m = 0; m < 64; ++m) s += b_lin[m * 64 + tid];
        bmean[tid] = s * (1.f / 64.f);
    }
}

// ---------------------------------------------------------------------------
// gemm_prep: 512 blocks x 256 threads (4 waves), 64 A-rows per block.
//  blocks 0..255  : Ppe[r][o]    = exp((source@W_s)[r][o])           f16
//                   Ppe[r][64+o] = (source@W_mean)[r][o] + bmean[o]  f16
//  blocks 256..511: Et[r][o] = exp((target@W_t)[r][o] + b_s[o] + b_t[o]) f32
//  A rows read f32 (full K upfront, 16 loads in flight), cvt f16 in-reg.
//  B staged fragment-major in LDS (conflict-free ds_read_b128 at l*16+imm).
// ---------------------------------------------------------------------------
__device__ __forceinline__ f16x8 cvt8(const float* p) {
    f32x4 x = *(const f32x4*)p;
    f32x4 y = *(const f32x4*)(p + 4);
    f16x8 h;
    h[0] = (_Float16)x[0]; h[1] = (_Float16)x[1]; h[2] = (_Float16)x[2]; h[3] = (_Float16)x[3];
    h[4] = (_Float16)y[0]; h[5] = (_Float16)y[1]; h[6] = (_Float16)y[2]; h[7] = (_Float16)y[3];
    return h;
}

__global__ __launch_bounds__(256, 2)
void gemm_prep(const float* __restrict__ source, const float* __restrict__ target,
               const _Float16* __restrict__ WcT, const _Float16* __restrict__ Wt16,
               const float* __restrict__ bmean, const float* __restrict__ b_s,
               const float* __restrict__ b_t,
               _Float16* __restrict__ Ppe, float* __restrict__ Et) {
    __shared__ _Float16 lds[32768];   // SRC path uses 64 KiB, TGT 32 KiB

    const int tid = threadIdx.x;
    const int w = tid >> 6, l = tid & 63;
    const int l15 = l & 15, lq = l >> 4;
    const int b = blockIdx.x;

    if (b < 256) {
        // ---------------- SRC path ----------------
        const int rb = b * 64;
        const float* arow = source + (size_t)(rb + w * 16 + l15) * 256;
        f16x8 af[8];
        #pragma unroll
        for (int s = 0; s < 8; ++s) af[s] = cvt8(arow + s * 32 + lq * 8);

        #pragma unroll
        for (int i = 0; i < 16; ++i) {
            int c = i * 256 + tid;                   // 4096 chunks
            int fi = c >> 6, lane = c & 63;
            int nt = fi >> 3, s = fi & 7;
            f16x8 v = *(const f16x8*)(WcT + (nt * 16 + (lane & 15)) * 256 + s * 32 + (lane >> 4) * 8);
            *(f16x8*)((char*)lds + c * 16) = v;
        }
        __syncthreads();

        const char* bb = (const char*)lds + l * 16;
        f32x4 acc[8] = {};
        #pragma unroll
        for (int s = 0; s < 8; ++s) {
            #pragma unroll
            for (int nt = 0; nt < 8; ++nt) {
                f16x8 bf = *(const f16x8*)(bb + nt * 8192 + s * 1024);
                acc[nt] = __builtin_amdgcn_mfma_f32_16x16x32_f16(af[s], bf, acc[nt], 0, 0, 0);
            }
        }

        float bmv[4];
        #pragma unroll
        for (int nt = 0; nt < 4; ++nt) bmv[nt] = bmean[nt * 16 + l15];
        #pragma unroll
        for (int j = 0; j < 4; ++j) {
            int row = rb + w * 16 + lq * 4 + j;
            #pragma unroll
            for (int nt = 0; nt < 4; ++nt) {
                // Ppe row = [Pe(64) | Pp(64)]; col expr identical for both halves
                Ppe[row * 128 + nt * 16 + l15]        = (_Float16)__expf(acc[nt][j]);
                Ppe[row * 128 + (nt + 4) * 16 + l15]  = (_Float16)(acc[nt + 4][j] + bmv[nt]);
            }
        }
    } else {
        // ---------------- TGT path ----------------
        const int rb = (b - 256) * 64;
        const float* arow = target + (size_t)(rb + w * 16 + l15) * 256;
        f16x8 af[8];
        #pragma unroll
        for (int s = 0; s < 8; ++s) af[s] = cvt8(arow + s * 32 + lq * 8);

        #pragma unroll
        for (int i = 0; i < 8; ++i) {
            int c = i * 256 + tid;                   // 2048 chunks
            int fi = c >> 6, lane = c & 63;
            int nt = fi >> 3, s = fi & 7;
            f16x8 v = *(const f16x8*)(Wt16 + (nt * 16 + (lane & 15)) * 256 + s * 32 + (lane >> 4) * 8);
            *(f16x8*)((char*)lds + c * 16) = v;
        }
        __syncthreads();

        const char* bb = (const char*)lds + l * 16;
        f32x4 acc[4] = {};
        #pragma unroll
        for (int s = 0; s < 8; ++s) {
            #pragma unroll
            for (int nt = 0; nt < 4; ++nt) {
                f16x8 bf = *(const f16x8*)(bb + nt * 8192 + s * 1024);
                acc[nt] = __builtin_amdgcn_mfma_f32_16x16x32_f16(af[s], bf, acc[nt], 0, 0, 0);
            }
        }

        float bsv[4];
        #pragma unroll
        for (int nt = 0; nt < 4; ++nt) {
            int col = nt * 16 + l15;
            bsv[nt] = b_s[col] + b_t[col];
        }
        #pragma unroll
        for (int j = 0; j < 4; ++j) {
            int row = rb + w * 16 + lq * 4 + j;
            #pragma unroll
            for (int nt = 0; nt < 4; ++nt)
                Et[row * 64 + nt * 16 + l15] = __expf(acc[nt][j] + bsv[nt]);
        }
    }
}

// ---------------------------------------------------------------------------
// epilogue: 2048 blocks x 256 threads; TWO target nodes per wave (64 rows).
// All index loads + gathers issued up front (32 gather pairs in flight per
// lane) to maximize memory-level parallelism; normal (cached) stores.
// Lane (lq,l15): group g handles 4 rows (lq) x 4 cols (l15*4..+3).
// out[r][o] = Pe[nb][o]*Et[n][o] / sum_o(Pe*Et) * Pp[nb][o]
// ---------------------------------------------------------------------------
__global__ __launch_bounds__(256)
void epilogue(const int* __restrict__ neighbors, const _Float16* __restrict__ Ppe,
              const float* __restrict__ Et, float* __restrict__ out) {
    const int tid = threadIdx.x;
    const int w = tid >> 6, l = tid & 63;
    const int lq = l >> 4, l15 = l & 15;
    const int n0 = blockIdx.x * 8 + w * 2;      // this wave: n0, n0+1
    const int co = l15 * 4;

    f32x4 et0 = *(const f32x4*)(Et + n0 * 64 + co);
    f32x4 et1 = *(const f32x4*)(Et + (n0 + 1) * 64 + co);

    int nb0[8], nb1[8];
    #pragma unroll
    for (int g = 0; g < 8; ++g) nb0[g] = neighbors[n0 * 32 + g * 4 + lq];
    #pragma unroll
    for (int g = 0; g < 8; ++g) nb1[g] = neighbors[(n0 + 1) * 32 + g * 4 + lq];

    f16x4 pe0[8], pp0[8], pe1[8], pp1[8];
    #pragma unroll
    for (int g = 0; g < 8; ++g) {
        pe0[g] = *(const f16x4*)(Ppe + nb0[g] * 128 + co);
        pp0[g] = *(const f16x4*)(Ppe + nb0[g] * 128 + 64 + co);
    }
    #pragma unroll
    for (int g = 0; g < 8; ++g) {
        pe1[g] = *(const f16x4*)(Ppe + nb1[g] * 128 + co);
        pp1[g] = *(const f16x4*)(Ppe + nb1[g] * 128 + 64 + co);
    }

    #pragma unroll
    for (int g = 0; g < 8; ++g) {
        float w0 = (float)pe0[g][0] * et0[0];
        float w1 = (float)pe0[g][1] * et0[1];
        float w2 = (float)pe0[g][2] * et0[2];
        float w3 = (float)pe0[g][3] * et0[3];
        float s = (w0 + w1) + (w2 + w3);
        s += __shfl_xor(s, 1);
        s += __shfl_xor(s, 2);
        s += __shfl_xor(s, 4);
        s += __shfl_xor(s, 8);
        float inv = 1.0f / s;
        f32x4 o;
        o[0] = w0 * inv * (float)pp0[g][0];
        o[1] = w1 * inv * (float)pp0[g][1];
        o[2] = w2 * inv * (float)pp0[g][2];
        o[3] = w3 * inv * (float)pp0[g][3];
        *(f32x4*)(out + (size_t)(n0 * 32 + g * 4 + lq) * 64 + co) = o;
    }
    #pragma unroll
    for (int g = 0; g < 8; ++g) {
        float w0 = (float)pe1[g][0] * et1[0];
        float w1 = (float)pe1[g][1] * et1[1];
        float w2 = (float)pe1[g][2] * et1[2];
        float w3 = (float)pe1[g][3] * et1[3];
        float s = (w0 + w1) + (w2 + w3);
        s += __shfl_xor(s, 1);
        s += __shfl_xor(s, 2);
        s += __shfl_xor(s, 4);
        s += __shfl_xor(s, 8);
        float inv = 1.0f / s;
        f32x4 o;
        o[0] = w0 * inv * (float)pp1[g][0];
        o[1] = w1 * inv * (float)pp1[g][1];
        o[2] = w2 * inv * (float)pp1[g][2];
        o[3] = w3 * inv * (float)pp1[g][3];
        *(f32x4*)(out + (size_t)((n0 + 1) * 32 + g * 4 + lq) * 64 + co) = o;
    }
}

// ---------------------------------------------------------------------------
extern "C" void kernel_launch(void* const* d_in, const int* in_sizes, int n_in,
                              void* d_out, int out_size, void* d_ws, size_t ws_size,
                              hipStream_t stream) {
    const float* source    = (const float*)d_in[0];
    const float* target    = (const float*)d_in[1];
    const int*   neighbors = (const int*)d_in[2];
    const float* W_lin     = (const float*)d_in[3];
    const float* b_lin     = (const float*)d_in[4];
    const float* W_s       = (const float*)d_in[5];
    const float* b_s       = (const float*)d_in[6];
    const float* W_t       = (const float*)d_in[7];
    const float* b_t       = (const float*)d_in[8];

    char* ws = (char*)d_ws;
    _Float16* Ppe   = (_Float16*)ws;                          // 4 MiB
    float*    Et    = (float*)(ws + (4u << 20));              // 4 MiB
    _Float16* WcT   = (_Float16*)(ws + (8u << 20));           // 64 KiB
    _Float16* Wt16  = (_Float16*)(ws + (8u << 20) + 65536);   // 32 KiB
    float*    bmean = (float*)(ws + (8u << 20) + 98304);      // 256 B
    float*    out   = (float*)d_out;

    prep_weights<<<128, 256, 0, stream>>>(W_lin, b_lin, W_s, W_t, WcT, Wt16, bmean);
    gemm_prep<<<512, 256, 0, stream>>>(source, target, WcT, Wt16, bmean, b_s, b_t,
                                       Ppe, Et);
    epilogue<<<2048, 256, 0, stream>>>(neighbors, Ppe, Et, out);
}